// Round 10
// baseline (252.119 us; speedup 1.0000x reference)
//
#include <hip/hip_runtime.h>
#include <stdint.h>
#include <math.h>

// RG-LRU: B=4, L=4096, D=1024.
//   r = sigmoid(x @ Wa^T + ba); i = sigmoid(x @ Wx^T + bx)
//   e = 8*r*log2(sigmoid(lmbd));  a = exp2(e);  b = sqrt(1-a^2)*i*x
//   h_t = a_t*h_{t-1} + b_t
//
// R13: scans/pack-consumers reverted to R7-exact (proven best, 246.5us).
//   GEMM rewritten to the 8-phase 256x256 schedule (guide T3+T4+T5):
//   BK=64, 8 waves (2Mx4N), 128KB double-buffered LDS, 4 phases per K-tile:
//   {stage 2 global_load_lds (tile kt+1) -> counted vmcnt(6) at the two
//    new-k-slice phases (never 0 in steady state) -> s_barrier ->
//    ds_read_b128 frags -> setprio(1) 16 MFMA setprio(0)}; 3 barriers/K-tile.
//   pack_all re-packs Xs/Ws so every stage op is a linear base+tid*16 copy
//   (LDS micro-layout = proven conflict-free 16-row fragment groups).

#define D_DIM 1024
#define L_DIM 4096
#define B_DIM 4
#define M_DIM (B_DIM * L_DIM)   // 16384
#define N_DIM (2 * D_DIM)       // 2048
#define K_DIM D_DIM             // 1024
#define NC 32
#define CL (L_DIM / NC)         // 128
#define L2E 1.4426950408889634f

typedef __attribute__((ext_vector_type(8))) short short8;
typedef __attribute__((ext_vector_type(4))) short short4v;
typedef __attribute__((ext_vector_type(4))) float float4v;

__device__ __forceinline__ unsigned short f2bf(float f) {
  unsigned u = __float_as_uint(f);
  u += 0x7fffu + ((u >> 16) & 1u);
  return (unsigned short)(u >> 16);
}
__device__ __forceinline__ float bf2f(unsigned short h) {
  return __uint_as_float((unsigned)h << 16);
}
__device__ __forceinline__ short f2h(float f) {
  _Float16 h = (_Float16)f;
  return __builtin_bit_cast(short, h);
}

#define NX16 (M_DIM * K_DIM / 8)       // 2097152 x-granules (16B each)
#define NW16 (N_DIM * K_DIM / 8)       // 262144 w-granules

// Pack fp32 [rows][1024] -> bf16 granule stream for the 256x64 K-tile stager.
// Granule u fields: g=u&63, mg=(u>>6)&7, ks=(u>>9)&1, H=(u>>10)&1,
// kt=(u>>11)&15, S=u>>15.  row = S*256+H*128+mg*16+(g&15),
// k = kt*64+ks*32+(g>>4)*8.  Reads stay 128B-granule coalesced (4 lanes x 32B
// per row), writes are 1KB-contiguous per wave.
__global__ void pack_all(const float* __restrict__ x, const float* __restrict__ Wa,
                         const float* __restrict__ Wx, short* __restrict__ Xs,
                         short* __restrict__ Ws) {
  int t = blockIdx.x * 256 + threadIdx.x;
  const float* src;
  short8* dst;
  int u;
  int m;
  if (t < NX16) {
    u = t; dst = (short8*)Xs;
    m = (u >> 15) * 256 + ((u >> 10) & 1) * 128 + ((u >> 6) & 7) * 16 + (u & 15);
    src = x;
  } else {
    u = t - NX16;
    if (u >= NW16) return;
    dst = (short8*)Ws;
    m = (u >> 15) * 256 + ((u >> 10) & 1) * 128 + ((u >> 6) & 7) * 16 + (u & 15);
    src = (m < D_DIM) ? Wa : (Wx - (size_t)D_DIM * K_DIM);
  }
  int k = ((u >> 11) & 15) * 64 + ((u >> 9) & 1) * 32 + ((u >> 4) & 3) * 8;
  const float4v* s4 = (const float4v*)(src + (size_t)m * 1024 + k);
  float4v v0 = s4[0], v1 = s4[1];
  short8 o;
  o[0] = (short)f2bf(v0.x); o[1] = (short)f2bf(v0.y);
  o[2] = (short)f2bf(v0.z); o[3] = (short)f2bf(v0.w);
  o[4] = (short)f2bf(v1.x); o[5] = (short)f2bf(v1.y);
  o[6] = (short)f2bf(v1.z); o[7] = (short)f2bf(v1.w);
  dst[u] = o;
}

// 256x256 tile, BK=64, 8 waves (wm=wave>>2 in {0,1}, wn=wave&3), 8-phase-style
// schedule: 4 phases/K-tile, counted vmcnt(6), double-buffered 2x64KB LDS.
// LDS per buffer: [X(A/B)][H][ks][grp(8)][granule(64)x16B] -> stage op
// (X,H,ks) = 8KB = one global_load_lds per thread, wave-uniform dst.
__global__ __launch_bounds__(512, 1) void gemm_gates(
    const short* __restrict__ Xs,
    const short* __restrict__ Ws,
    const float* __restrict__ xf,
    const float* __restrict__ ba,
    const float* __restrict__ bx,
    const float* __restrict__ lmbd,
    short* __restrict__ e_out,          // [16384,1024] fp16: 8*r*log2(sig(lmbd))
    unsigned short* __restrict__ g_out) // [16384,1024] bf16: i*x
{
  __shared__ __align__(16) char smem[131072];   // 2 x 64KB buffers; epilogue aliases

  // 512 blocks, 512 % 8 == 0 -> chunked XCD remap is bijective.
  const int bid = blockIdx.y * 8 + blockIdx.x;        // linear, n fastest
  const int nb  = (bid & 7) * 64 + (bid >> 3);        // XCD-chunked
  const int tile_n = (nb & 7) * 256;
  const int tile_m = (nb >> 3) * 256;
  const int tid  = threadIdx.x;
  const int wave = tid >> 6;
  const int lane = tid & 63;
  const int wm = wave >> 2;      // 0..1  (m-half, 128 rows)
  const int wn = wave & 3;       // 0..3  (n-quarter, 64 cols)
  const size_t mS = (size_t)(tile_m >> 8);
  const size_t nS = (size_t)(tile_n >> 8);

  float4v acc[8][4] = {};

  // Stage op: (X: 0=A,1=B; H; ks) of tile kt -> buffer bufN.
  // Source granule base = (((S*16+kt)*2+H)*2+ks)*512 ; thread adds tid.
  // LDS dst = bufN*64KB + ((X*2+H)*2+ks)*8KB + wave*1KB (+lane*16 by HW).
#define STAGE(Xsel, Hs, kss, ktN, bufN)                                        \
  do {                                                                         \
    const size_t bg_ = ((((Xsel ? nS : mS) * 16 + (size_t)(ktN)) * 2 +         \
                        (size_t)(Hs)) * 2 + (size_t)(kss)) * 512;              \
    const short* sp_ = (Xsel ? Ws : Xs) + (bg_ + (size_t)tid) * 8;             \
    __builtin_amdgcn_global_load_lds(                                          \
        (const __attribute__((address_space(1))) void*)sp_,                    \
        (__attribute__((address_space(3))) void*)(smem + (bufN) * 65536 +      \
            (((Xsel) * 2 + (Hs)) * 2 + (kss)) * 8192 + wave * 1024),           \
        16, 0, 0);                                                             \
  } while (0)

  // Prologue: tile 0 -> buf0, full drain (only vmcnt(0) in the kernel).
#pragma unroll
  for (int X = 0; X < 2; ++X)
#pragma unroll
    for (int H = 0; H < 2; ++H)
#pragma unroll
      for (int ks = 0; ks < 2; ++ks)
        STAGE(X, H, ks, 0, 0);
  asm volatile("s_waitcnt vmcnt(0)" ::: "memory");
  __builtin_amdgcn_sched_barrier(0);
  __builtin_amdgcn_s_barrier();

  const int aBase = (wm * 2) * 8192;                   // + ks*8192
  const int bBase = ((2 + (wn >> 1)) * 2) * 8192;      // + ks*8192
  const int bGrp  = (wn & 1) * 4;

  for (int kt = 0; kt < 16; ++kt) {
    const int cur = kt & 1;
    const int nxt = cur ^ 1;
    const bool stg = (kt < 15);
    const char* buf = smem + cur * 65536;
    short8 af[4], bf[4];

    // ---------------- phase 1: ks=0, mi 0..3 ----------------
    if (stg) { STAGE(0, 0, 0, kt + 1, nxt); STAGE(0, 1, 0, kt + 1, nxt); }
    if (stg) asm volatile("s_waitcnt vmcnt(6)" ::: "memory");
    else     asm volatile("s_waitcnt vmcnt(4)" ::: "memory");
    __builtin_amdgcn_sched_barrier(0);
    __builtin_amdgcn_s_barrier();
#pragma unroll
    for (int i = 0; i < 4; ++i)
      af[i] = *(const short8*)(buf + aBase + i * 1024 + lane * 16);
#pragma unroll
    for (int i = 0; i < 4; ++i)
      bf[i] = *(const short8*)(buf + bBase + (bGrp + i) * 1024 + lane * 16);
    __builtin_amdgcn_s_setprio(1);
#pragma unroll
    for (int i = 0; i < 4; ++i)
#pragma unroll
      for (int ni = 0; ni < 4; ++ni)
        acc[i][ni] = __builtin_amdgcn_mfma_f32_16x16x32_bf16(af[i], bf[ni], acc[i][ni], 0, 0, 0);
    __builtin_amdgcn_s_setprio(0);

    // ---------------- phase 2: ks=0, mi 4..7 ----------------
    if (stg) { STAGE(1, 0, 0, kt + 1, nxt); STAGE(1, 1, 0, kt + 1, nxt); }
#pragma unroll
    for (int i = 0; i < 4; ++i)
      af[i] = *(const short8*)(buf + aBase + (4 + i) * 1024 + lane * 16);
    __builtin_amdgcn_s_setprio(1);
#pragma unroll
    for (int i = 0; i < 4; ++i)
#pragma unroll
      for (int ni = 0; ni < 4; ++ni)
        acc[4 + i][ni] = __builtin_amdgcn_mfma_f32_16x16x32_bf16(af[i], bf[ni], acc[4 + i][ni], 0, 0, 0);
    __builtin_amdgcn_s_setprio(0);

    // ---------------- phase 3: ks=1, mi 0..3 ----------------
    if (stg) { STAGE(0, 0, 1, kt + 1, nxt); STAGE(0, 1, 1, kt + 1, nxt); }
    if (stg) asm volatile("s_waitcnt vmcnt(6)" ::: "memory");
    else     asm volatile("s_waitcnt vmcnt(0)" ::: "memory");
    __builtin_amdgcn_sched_barrier(0);
    __builtin_amdgcn_s_barrier();
#pragma unroll
    for (int i = 0; i < 4; ++i)
      af[i] = *(const short8*)(buf + aBase + 8192 + i * 1024 + lane * 16);
#pragma unroll
    for (int i = 0; i < 4; ++i)
      bf[i] = *(const short8*)(buf + bBase + 8192 + (bGrp + i) * 1024 + lane * 16);
    __builtin_amdgcn_s_setprio(1);
#pragma unroll
    for (int i = 0; i < 4; ++i)
#pragma unroll
      for (int ni = 0; ni < 4; ++ni)
        acc[i][ni] = __builtin_amdgcn_mfma_f32_16x16x32_bf16(af[i], bf[ni], acc[i][ni], 0, 0, 0);
    __builtin_amdgcn_s_setprio(0);

    // ---------------- phase 4: ks=1, mi 4..7 ----------------
    if (stg) { STAGE(1, 0, 1, kt + 1, nxt); STAGE(1, 1, 1, kt + 1, nxt); }
#pragma unroll
    for (int i = 0; i < 4; ++i)
      af[i] = *(const short8*)(buf + aBase + 8192 + (4 + i) * 1024 + lane * 16);
    __builtin_amdgcn_s_setprio(1);
#pragma unroll
    for (int i = 0; i < 4; ++i)
#pragma unroll
      for (int ni = 0; ni < 4; ++ni)
        acc[4 + i][ni] = __builtin_amdgcn_mfma_f32_16x16x32_bf16(af[i], bf[ni], acc[4 + i][ni], 0, 0, 0);
    __builtin_amdgcn_s_setprio(0);
    __builtin_amdgcn_s_barrier();   // frees buf[cur] for next iter's staging
  }
#undef STAGE

  // ---- Epilogue: per-wave 128x64 transpose through LDS (stride 68 floats),
  // proven R7 code extended to mi 0..7. All compute reads finished (final
  // barrier above); Ts regions are per-wave disjoint.
  float* Ts = (float*)smem + (size_t)wave * (16 * 68);
  const int row16 = lane & 15;
  const int quad  = lane >> 4;
  const int colg = (lane & 15) * 4;
  const int rrow = lane >> 4;
  const bool is_a = (tile_n < D_DIM);
  const int ch0 = (is_a ? tile_n : tile_n - D_DIM) + wn * 64 + colg;

  float4v bias4, la84;
  if (is_a) {
    bias4 = *(const float4v*)(ba + ch0);
    float4v lm4 = *(const float4v*)(lmbd + ch0);
#pragma unroll
    for (int k = 0; k < 4; ++k)
      la84[k] = -8.0f * __builtin_amdgcn_logf(1.0f + __builtin_amdgcn_exp2f(-lm4[k] * L2E));
  } else {
    bias4 = *(const float4v*)(bx + ch0);
  }

#pragma unroll
  for (int mi = 0; mi < 8; ++mi) {
#pragma unroll
    for (int ni = 0; ni < 4; ++ni)
#pragma unroll
      for (int r = 0; r < 4; ++r)
        Ts[(quad * 4 + r) * 68 + ni * 16 + row16] = acc[mi][ni][r];
#pragma unroll
    for (int j = 0; j < 4; ++j) {
      int lr = j * 4 + rrow;                     // 0..15 local row
      float4v z = *(const float4v*)&Ts[lr * 68 + colg];
      size_t gm = (size_t)(tile_m + wm * 128 + mi * 16 + lr);
      short4v o;
      if (is_a) {
#pragma unroll
        for (int k = 0; k < 4; ++k) {
          float s = __builtin_amdgcn_rcpf(1.0f + __builtin_amdgcn_exp2f(-(z[k] + bias4[k]) * L2E));
          o[k] = f2h(s * la84[k]);
        }
        *(short4v*)(e_out + gm * D_DIM + ch0) = o;
      } else {
        float4v xv = *(const float4v*)(xf + gm * D_DIM + ch0);
#pragma unroll
        for (int k = 0; k < 4; ++k) {
          float s = __builtin_amdgcn_rcpf(1.0f + __builtin_amdgcn_exp2f(-(z[k] + bias4[k]) * L2E));
          o[k] = (short)f2bf(s * xv[k]);
        }
        *(short4v*)((short*)g_out + gm * D_DIM + ch0) = o;
      }
    }
  }
}

// Phase 1: per-chunk (P = prod a, Q = local scan from 0). a = exp2(e).
// Byte-identical to R7.
__global__ void scan_phase1(const short* __restrict__ e, const unsigned short* __restrict__ g,
                            float* __restrict__ P, float* __restrict__ Q) {
  int d = blockIdx.x * 256 + threadIdx.x;
  int c = blockIdx.y;
  int b = blockIdx.z;
  const size_t base = ((size_t)(b * L_DIM + c * CL)) * D_DIM + d;
  float Pv = 1.0f, Qv = 0.0f;
#pragma unroll 4
  for (int t = 0; t < CL; ++t) {
    float ev = (float)__builtin_bit_cast(_Float16, e[base + (size_t)t * D_DIM]);
    float at = __builtin_amdgcn_exp2f(ev);
    float gv = bf2f(g[base + (size_t)t * D_DIM]);
    float bt = sqrtf(fmaxf(1.0f - at * at, 0.0f)) * gv;
    Qv = fmaf(at, Qv, bt);
    Pv *= at;
  }
  int idx = (b * NC + c) * D_DIM + d;
  P[idx] = Pv;
  Q[idx] = Qv;
}

// Phase 3: lookback prefix over earlier chunks, replay chunk, write y.
// Byte-identical to R7.
__global__ void scan_phase3(const short* __restrict__ e, const unsigned short* __restrict__ g,
                            const float* __restrict__ P, const float* __restrict__ Q,
                            float* __restrict__ y) {
  int d = blockIdx.x * 256 + threadIdx.x;
  int c = blockIdx.y;
  int b = blockIdx.z;
  float h = 0.0f;
#pragma unroll 4
  for (int cc = 0; cc < c; ++cc) {
    int idx = (b * NC + cc) * D_DIM + d;
    h = fmaf(P[idx], h, Q[idx]);
  }
  const size_t base = ((size_t)(b * L_DIM + c * CL)) * D_DIM + d;
#pragma unroll 4
  for (int t = 0; t < CL; ++t) {
    float ev = (float)__builtin_bit_cast(_Float16, e[base + (size_t)t * D_DIM]);
    float at = __builtin_amdgcn_exp2f(ev);
    float gv = bf2f(g[base + (size_t)t * D_DIM]);
    float bt = sqrtf(fmaxf(1.0f - at * at, 0.0f)) * gv;
    h = fmaf(at, h, bt);
    y[base + (size_t)t * D_DIM] = h;
  }
}

extern "C" void kernel_launch(void* const* d_in, const int* in_sizes, int n_in,
                              void* d_out, int out_size, void* d_ws, size_t ws_size,
                              hipStream_t stream) {
  const float* x    = (const float*)d_in[0];
  const float* Wa   = (const float*)d_in[1];
  const float* Wx   = (const float*)d_in[2];
  const float* ba   = (const float*)d_in[3];
  const float* bx   = (const float*)d_in[4];
  const float* lmbd = (const float*)d_in[5];
  float* y = (float*)d_out;

  char* ws = (char*)d_ws;
  short* Xs             = (short*)ws;                        // 32 MiB packed bf16 x
  short* Wsz            = (short*)(ws + 33554432);           //  4 MiB packed bf16 [Wa;Wx]
  short* e_buf          = (short*)(ws + 37748736);           // 32 MiB fp16 e
  unsigned short* g_buf = (unsigned short*)(ws + 71303168);  // 32 MiB bf16 g
  float* P              = (float*)(ws + 104857600);          // 512 KiB
  float* Q              = (float*)(ws + 105381888);          // 512 KiB

  pack_all<<<(NX16 + NW16) / 256, 256, 0, stream>>>(x, Wa, Wx, Xs, Wsz);

  dim3 gg(N_DIM / 256, M_DIM / 256);   // (8, 64), n fastest linear order
  gemm_gates<<<gg, 512, 0, stream>>>(Xs, Wsz, x, ba, bx, lmbd, e_buf, g_buf);

  dim3 sg(D_DIM / 256, NC, B_DIM);     // (4, 32, 4)
  scan_phase1<<<sg, 256, 0, stream>>>(e_buf, g_buf, P, Q);
  scan_phase3<<<sg, 256, 0, stream>>>(e_buf, g_buf, P, Q, y);
}